// Round 3
// baseline (2292.400 us; speedup 1.0000x reference)
//
#include <hip/hip_runtime.h>
#include <math.h>

#define IN_DIM 128
#define H1 64
#define H2 32
#define NC 8
#define SCAN_CH 1024   // elements per scan block (256 threads x 4)
#define NB_MAX 512     // max buckets (n <= 131072)
#define BLK 512        // edge partition blocks
#define CAP 12288      // LDS staging capacity per bucket (entries)

typedef unsigned int u32;

__device__ __forceinline__ float bf_lo(u32 u) { return __uint_as_float(u << 16); }
__device__ __forceinline__ float bf_hi(u32 u) { return __uint_as_float(u & 0xffff0000u); }
__device__ __forceinline__ unsigned short f2b(float f) {  // RNE float->bf16
  u32 u = __float_as_uint(f);
  u += 0x7fffu + ((u >> 16) & 1u);
  return (unsigned short)(u >> 16);
}

// ---------------- P1: per-block bucket histogram (LDS atomics only) ----------------
// bucket(d) = d >> 8 (256 nodes per bucket).

__global__ __launch_bounds__(256) void k_hist(const int* __restrict__ dst,
                                              int* __restrict__ bh,
                                              int E, int EPB, int NBk) {
  __shared__ int h[NB_MAX];
  int k = blockIdx.x, tid = threadIdx.x;
  for (int i = tid; i < NBk; i += 256) h[i] = 0;
  __syncthreads();
  int st = k * EPB, en = min(E, st + EPB);
  for (int i = st + tid; i < en; i += 256)
    atomicAdd(&h[((u32)dst[i]) >> 8], 1);
  __syncthreads();
  for (int b = tid; b < NBk; b += 256) bh[b * BLK + k] = h[b];
}

// ---- generic 3-phase exclusive scan of A[L] -> S[L], S[L] = total ----

__global__ __launch_bounds__(256) void k_gsc1(const int* __restrict__ A,
                                              int* __restrict__ bsum, int L) {
  int b = blockIdx.x, tid = threadIdx.x;
  int i0 = b * SCAN_CH + tid * 4;
  int s = 0;
  if (i0 + 3 < L) {
    int4 v = *(const int4*)(A + i0);
    s = v.x + v.y + v.z + v.w;
  } else {
    for (int i = i0; i < L; ++i) s += A[i];
  }
  __shared__ int red[256];
  red[tid] = s;
  __syncthreads();
  for (int d = 128; d > 0; d >>= 1) {
    if (tid < d) red[tid] += red[tid + d];
    __syncthreads();
  }
  if (tid == 0) bsum[b] = red[0];
}

__global__ __launch_bounds__(256) void k_gsc2(const int* __restrict__ bsum,
                                              int* __restrict__ bbase,
                                              int* __restrict__ S, int nbk, int L) {
  __shared__ int part[256];
  int tid = threadIdx.x;
  int chunk = (nbk + 255) / 256;
  int st = tid * chunk, en = min(st + chunk, nbk);
  int s = 0;
  for (int i = st; i < en; ++i) s += bsum[i];
  part[tid] = s;
  __syncthreads();
  for (int d = 1; d < 256; d <<= 1) {
    int t = (tid >= d) ? part[tid - d] : 0;
    __syncthreads();
    part[tid] += t;
    __syncthreads();
  }
  int base = (tid == 0) ? 0 : part[tid - 1];
  for (int i = st; i < en; ++i) { bbase[i] = base; base += bsum[i]; }
  if (tid == 255) S[L] = part[255];
}

__global__ __launch_bounds__(256) void k_gsc3(const int* __restrict__ A,
                                              const int* __restrict__ bbase,
                                              int* __restrict__ S, int L) {
  int b = blockIdx.x, tid = threadIdx.x;
  int i0 = b * SCAN_CH + tid * 4;
  int e0 = 0, e1 = 0, e2 = 0, e3 = 0;
  if (i0 + 3 < L) {
    int4 v = *(const int4*)(A + i0);
    e0 = v.x; e1 = v.y; e2 = v.z; e3 = v.w;
  } else {
    if (i0 + 0 < L) e0 = A[i0 + 0];
    if (i0 + 1 < L) e1 = A[i0 + 1];
    if (i0 + 2 < L) e2 = A[i0 + 2];
    if (i0 + 3 < L) e3 = A[i0 + 3];
  }
  __shared__ int part[256];
  part[tid] = e0 + e1 + e2 + e3;
  __syncthreads();
  for (int d = 1; d < 256; d <<= 1) {
    int t = (tid >= d) ? part[tid - d] : 0;
    __syncthreads();
    part[tid] += t;
    __syncthreads();
  }
  int base = bbase[b] + ((tid == 0) ? 0 : part[tid - 1]);
  int o0 = base, o1 = o0 + e0, o2 = o1 + e1, o3 = o2 + e2;
  if (i0 + 3 < L) {
    int4 o; o.x = o0; o.y = o1; o.z = o2; o.w = o3;
    *(int4*)(S + i0) = o;
  } else {
    if (i0 + 0 < L) S[i0 + 0] = o0;
    if (i0 + 1 < L) S[i0 + 1] = o1;
    if (i0 + 2 < L) S[i0 + 2] = o2;
    if (i0 + 3 < L) S[i0 + 3] = o3;
  }
}

// ---------------- P3: bucket scatter (LDS cursors, disjoint global ranges) ----------------
// packed entry: bits[0,17) = src, bits[17,25) = local node id within bucket.

__global__ __launch_bounds__(256) void k_scatter(const int* __restrict__ src,
                                                 const int* __restrict__ dst,
                                                 const int* __restrict__ S,
                                                 u32* __restrict__ packed,
                                                 int E, int EPB, int NBk) {
  __shared__ int cur[NB_MAX];
  int k = blockIdx.x, tid = threadIdx.x;
  for (int b = tid; b < NBk; b += 256) cur[b] = S[b * BLK + k];
  __syncthreads();
  int st = k * EPB, en = min(E, st + EPB);
  for (int i = st + tid; i < en; i += 256) {
    int d = dst[i];
    int b = ((u32)d) >> 8;
    int pos = atomicAdd(&cur[b], 1);
    packed[pos] = (((u32)d & 255u) << 17) | (u32)src[i];
  }
}

// ---------------- P4 (R16): per-bucket sort by (dst-half, src-tile) + dinv ----------------
// csr2 keeps the full packed entry (dst_local<<17 | src), ordered so that each
// half-bucket's edges are contiguous and ascending in src>>10. This gives the
// Z-sweep kernels a globally synchronized march through src-space (L2 window).

__global__ __launch_bounds__(256) void k_build2(const u32* __restrict__ packed,
                                                const int* __restrict__ S,
                                                u32* __restrict__ csr2,
                                                int* __restrict__ off2h,
                                                float* __restrict__ dinv,
                                                int n, int NBk, int NT) {
  __shared__ int cnt[256];   // per dst_local degree (for dinv)
  __shared__ int bins[256];  // (half, src_tile) counts; 2*NT <= 256
  __shared__ int tmp[256];
  __shared__ int cur[256];
  __shared__ u32 sbuf[CAP];  // 48 KB staging
  int b = blockIdx.x, tid = threadIdx.x;
  int r0 = S[b * BLK];
  int r1 = S[(b + 1) * BLK];  // last bucket: S[L] = E
  int m = r1 - r0;
  cnt[tid] = 0;
  bins[tid] = 0;
  __syncthreads();
  for (int i = r0 + tid; i < r1; i += 256) {
    u32 p = packed[i];
    int dl = (int)(p >> 17);
    int key = ((dl >> 7) ? NT : 0) + (int)((p & 0x1FFFFu) >> 10);
    atomicAdd(&cnt[dl], 1);
    atomicAdd(&bins[key], 1);
  }
  __syncthreads();
  int v = bins[tid];
  tmp[tid] = v;
  __syncthreads();
  for (int d = 1; d < 256; d <<= 1) {
    int t = (tid >= d) ? tmp[tid - d] : 0;
    __syncthreads();
    tmp[tid] += t;
    __syncthreads();
  }
  cur[tid] = tmp[tid] - v;  // exclusive prefix of bins
  int node = b * 256 + tid;
  if (node < n) dinv[node] = rsqrtf((float)(cnt[tid] + 1));  // +1 self-loop
  if (tid == 0) off2h[b] = r0 + tmp[NT - 1];  // lower-half edge count boundary
  __syncthreads();
  if (m <= CAP) {
    for (int i = r0 + tid; i < r1; i += 256) {
      u32 p = packed[i];
      int dl = (int)(p >> 17);
      int key = ((dl >> 7) ? NT : 0) + (int)((p & 0x1FFFFu) >> 10);
      int pos = atomicAdd(&cur[key], 1);
      sbuf[pos] = p;
    }
    __syncthreads();
    for (int j = tid; j < m; j += 256)
      csr2[r0 + j] = sbuf[j];
  } else {
    // fallback: scattered global writes (statistically unreachable)
    for (int i = r0 + tid; i < r1; i += 256) {
      u32 p = packed[i];
      int dl = (int)(p >> 17);
      int key = ((dl >> 7) ? NT : 0) + (int)((p & 0x1FFFFu) >> 10);
      int pos = atomicAdd(&cur[key], 1);
      csr2[r0 + pos] = p;
    }
  }
}

// ---------------- projection 1: h1p = bf16(dinv * (x @ W1^T))  [n,128]->[n,64] ----------------

__global__ void k_proj1(const float4* __restrict__ x4, const float* __restrict__ W1,
                        const float* __restrict__ dinv,
                        unsigned short* __restrict__ h1p, int n) {
  __shared__ float xs[16][IN_DIM];
  __shared__ float wt[IN_DIM][H1 + 1];
  int tid = threadIdx.x;
  int row0 = blockIdx.x * 16;

  for (int i = tid; i < (H1 * IN_DIM / 4); i += 256) {
    float4 w = ((const float4*)W1)[i];
    int o = (i * 4) / IN_DIM;
    int k = (i * 4) % IN_DIM;
    wt[k + 0][o] = w.x; wt[k + 1][o] = w.y; wt[k + 2][o] = w.z; wt[k + 3][o] = w.w;
  }
  for (int i = tid; i < 16 * IN_DIM / 4; i += 256) {
    int r = (i * 4) / IN_DIM, k = (i * 4) % IN_DIM;
    int row = row0 + r;
    if (row < n)
      *((float4*)&xs[r][k]) = x4[(size_t)row * (IN_DIM / 4) + k / 4];
  }
  __syncthreads();

  int o = tid & 63, rq = tid >> 6;
  float a0 = 0.f, a1 = 0.f, a2 = 0.f, a3 = 0.f;
  for (int k = 0; k < IN_DIM; ++k) {
    float w = wt[k][o];
    a0 += xs[rq * 4 + 0][k] * w;
    a1 += xs[rq * 4 + 1][k] * w;
    a2 += xs[rq * 4 + 2][k] * w;
    a3 += xs[rq * 4 + 3][k] * w;
  }
  int r = row0 + rq * 4;
  if (r + 0 < n) h1p[(size_t)(r + 0) * H1 + o] = f2b(a0 * dinv[r + 0]);
  if (r + 1 < n) h1p[(size_t)(r + 1) * H1 + o] = f2b(a1 * dinv[r + 1]);
  if (r + 2 < n) h1p[(size_t)(r + 2) * H1 + o] = f2b(a2 * dinv[r + 2]);
  if (r + 3 < n) h1p[(size_t)(r + 3) * H1 + o] = f2b(a3 * dinv[r + 3]);
}

// ---------------- Z1 (R16): src-sweep scatter-agg layer 1 + bias/relu + proj2 ----------------
// Block zb owns 128 dst nodes (bucket zb>>1, half zb&1). Sweeps its edges in
// ascending src>>10 order; all blocks co-resident and uniform => chip-wide
// moving src window => gathers are L2 hits (kills the 2.3G miss-request wall).
// Accumulation: ds_add_f32 into acc[128][65] (stride-65 spreads banks; atomics
// are fire-and-forget so the sweep never stalls on lgkmcnt).

__global__ __launch_bounds__(256) void k_zagg1(
    const uint4* __restrict__ hp4,             // h1p rows: 128B = 8 x uint4... (8 lanes x 16B)
    const unsigned short* __restrict__ h1s,    // same buffer, u16 view (self term)
    const float* __restrict__ dinv,
    const int* __restrict__ S, const int* __restrict__ off2h,
    const u32* __restrict__ csr2,
    const float* __restrict__ b1, const float* __restrict__ W2,
    unsigned short* __restrict__ h2p, int n) {
  __shared__ float acc[128][H1 + 1];
  __shared__ float wt[H1][H2 + 1];
  int tid = threadIdx.x;
  int zb = blockIdx.x, b = zb >> 1, H = zb & 1;

  for (int i = tid; i < H2 * H1 / 4; i += 256) {
    float4 w = ((const float4*)W2)[i];
    int o = (i * 4) / H1, k = (i * 4) % H1;
    wt[k + 0][o] = w.x; wt[k + 1][o] = w.y; wt[k + 2][o] = w.z; wt[k + 3][o] = w.w;
  }
  for (int i = tid; i < 128 * (H1 + 1); i += 256) ((float*)acc)[i] = 0.f;
  __syncthreads();

  int e0 = H ? off2h[b] : S[b * BLK];
  int e1 = H ? S[(b + 1) * BLK] : off2h[b];
  int lane = tid & 63, wv = tid >> 6;
  int es = lane >> 3, j = lane & 7;   // 8 edges/instr, 8 lanes x 16B per edge

  for (int base = e0 + wv * 8; base < e1; base += 32) {
    int ei = base + es;
    if (ei < e1) {
      u32 p = csr2[ei];
      int src = (int)(p & 0x1FFFFu);
      int dl = (int)((p >> 17) & 127u);
      uint4 v = hp4[(size_t)src * (H1 / 8) + j];
      float* ap = &acc[dl][8 * j];
      atomicAdd(ap + 0, bf_lo(v.x)); atomicAdd(ap + 1, bf_hi(v.x));
      atomicAdd(ap + 2, bf_lo(v.y)); atomicAdd(ap + 3, bf_hi(v.y));
      atomicAdd(ap + 4, bf_lo(v.z)); atomicAdd(ap + 5, bf_hi(v.z));
      atomicAdd(ap + 6, bf_lo(v.w)); atomicAdd(ap + 7, bf_hi(v.w));
    }
  }
  __syncthreads();

  int node0 = b * 256 + H * 128;
  // E1: add self (table has dinv folded), scale, bias, relu -> back into acc
  for (int idx = tid; idx < 128 * H1; idx += 256) {
    int nl = idx >> 6, k = idx & 63;
    int node = node0 + nl;
    if (node < n) {
      float self = __uint_as_float(((u32)h1s[(size_t)node * H1 + k]) << 16);
      acc[nl][k] = fmaxf(dinv[node] * (acc[nl][k] + self) + b1[k], 0.f);
    }
  }
  __syncthreads();
  // E2: proj2 -> h2p (dinv folded for next layer's table)
  for (int t = 0; t < 16; ++t) {
    int nl = wv * 32 + t * 2 + (lane >> 5);
    int node = node0 + nl;
    int o = lane & 31;
    if (node < n) {
      float a = 0.f;
#pragma unroll
      for (int k = 0; k < H1; ++k) a += acc[nl][k] * wt[k][o];
      h2p[(size_t)node * H2 + o] = f2b(a * dinv[node]);
    }
  }
}

// ---------------- Z2 (R16): src-sweep scatter-agg layer 2 + b2 + gates + leaf ----------------

__global__ __launch_bounds__(256) void k_zagg2(
    const uint4* __restrict__ hp4,             // h2p rows: 64B = 4 x uint4
    const unsigned short* __restrict__ h2s,    // u16 view (self term)
    const float* __restrict__ dinv,
    const int* __restrict__ S, const int* __restrict__ off2h,
    const u32* __restrict__ csr2,
    const float* __restrict__ b2, const float* __restrict__ gate_w,
    const float* __restrict__ gate_b, const float* __restrict__ leaf_w,
    float* __restrict__ out, int n) {
  __shared__ float acc[128][H2 + 1];
  __shared__ float gwt[H2][H2 + 1];  // gate_w transposed
  __shared__ float lws[H2][NC + 1];
  __shared__ float rowg[4][2][H2 + 1];  // per-wave gate scratch (2 nodes)
  int tid = threadIdx.x;
  int zb = blockIdx.x, b = zb >> 1, H = zb & 1;

  {
    float4 w = ((const float4*)gate_w)[tid];  // H2*H2/4 == 256
    int jj = (tid * 4) / H2, k = (tid * 4) % H2;
    gwt[k + 0][jj] = w.x; gwt[k + 1][jj] = w.y; gwt[k + 2][jj] = w.z; gwt[k + 3][jj] = w.w;
  }
  lws[tid >> 3][tid & 7] = leaf_w[tid];  // H2*NC == 256
  for (int i = tid; i < 128 * (H2 + 1); i += 256) ((float*)acc)[i] = 0.f;
  __syncthreads();

  int e0 = H ? off2h[b] : S[b * BLK];
  int e1 = H ? S[(b + 1) * BLK] : off2h[b];
  int lane = tid & 63, wv = tid >> 6;
  int es = lane >> 2, j = lane & 3;   // 16 edges/instr, 4 lanes x 16B per edge

  for (int base = e0 + wv * 16; base < e1; base += 64) {
    int ei = base + es;
    if (ei < e1) {
      u32 p = csr2[ei];
      int src = (int)(p & 0x1FFFFu);
      int dl = (int)((p >> 17) & 127u);
      uint4 v = hp4[(size_t)src * (H2 / 8) + j];
      float* ap = &acc[dl][8 * j];
      atomicAdd(ap + 0, bf_lo(v.x)); atomicAdd(ap + 1, bf_hi(v.x));
      atomicAdd(ap + 2, bf_lo(v.y)); atomicAdd(ap + 3, bf_hi(v.y));
      atomicAdd(ap + 4, bf_lo(v.z)); atomicAdd(ap + 5, bf_hi(v.z));
      atomicAdd(ap + 6, bf_lo(v.w)); atomicAdd(ap + 7, bf_hi(v.w));
    }
  }
  __syncthreads();

  int node0 = b * 256 + H * 128;
  // E1: add self, scale by dinv, + b2 (no relu) -> back into acc
  for (int idx = tid; idx < 128 * H2; idx += 256) {
    int nl = idx >> 5, k = idx & 31;
    int node = node0 + nl;
    if (node < n) {
      float self = __uint_as_float(((u32)h2s[(size_t)node * H2 + k]) << 16);
      acc[nl][k] = dinv[node] * (acc[nl][k] + self) + b2[k];
    }
  }
  __syncthreads();
  // E2+E3 per node-pair: gates (sigmoid) then leaf matmul; all within-wave
  for (int t = 0; t < 16; ++t) {
    int hf = lane >> 5;                 // which of the 2 nodes this half handles
    int nl = wv * 32 + t * 2 + hf;
    int node = node0 + nl;
    int o = lane & 31;
    float g = 0.f;
#pragma unroll
    for (int k = 0; k < H2; ++k) g += acc[nl][k] * gwt[k][o];
    rowg[wv][hf][o] = 1.0f / (1.0f + __expf(-(g + gate_b[o])));
    // within-wave LDS write->read (lockstep, compiler inserts lgkmcnt)
    int c = lane & 7, gi = (lane >> 3) & 3;
    float a = 0.f;
#pragma unroll
    for (int j4 = 0; j4 < 8; ++j4) {
      int jj = gi * 8 + j4;
      a += rowg[wv][hf][jj] * lws[jj][c];
    }
    a += __shfl_xor(a, 8, 64);
    a += __shfl_xor(a, 16, 64);
    if ((lane & 31) < 8 && node < n) out[(size_t)node * NC + c] = a;
  }
}

// ---------------- host ----------------

extern "C" void kernel_launch(void* const* d_in, const int* in_sizes, int n_in,
                              void* d_out, int out_size, void* d_ws, size_t ws_size,
                              hipStream_t stream) {
  const float* x  = (const float*)d_in[0];
  const int*   ei = (const int*)d_in[1];
  const float* W1 = (const float*)d_in[2];
  const float* b1 = (const float*)d_in[3];
  const float* W2 = (const float*)d_in[4];
  const float* b2 = (const float*)d_in[5];
  const float* gw = (const float*)d_in[6];
  const float* gb = (const float*)d_in[7];
  const float* lw = (const float*)d_in[8];
  float* out = (float*)d_out;

  int n = in_sizes[0] / IN_DIM;
  int E = in_sizes[1] / 2;
  const int* src  = ei;
  const int* dstp = ei + E;

  int NBk = (n + 255) >> 8;                    // buckets of 256 nodes
  int NT  = (n + 1023) >> 10;                  // src tiles of 1024 nodes (<=128)
  int EPB = (E + BLK - 1) / BLK;               // edges per partition block
  int L   = NBk * BLK;                         // blockhist entries
  int nbs = (L + SCAN_CH - 1) / SCAN_CH;       // scan blocks

  // workspace layout (16B-aligned chunks)
  size_t n4  = ((size_t)n + 3) & ~(size_t)3;
  size_t np4 = ((size_t)n + 1 + 3) & ~(size_t)3;
  size_t E4  = ((size_t)E + 3) & ~(size_t)3;
  size_t L4  = ((size_t)L + 1 + 3) & ~(size_t)3;
  size_t nbs4 = ((size_t)nbs + 3) & ~(size_t)3;
  char* w = (char*)d_ws;
  u32* csr2   = (u32*)w;   w += E4 * 4;
  u32* packed = (u32*)w;   w += E4 * 4;
  int* bh     = (int*)w;   w += L4 * 4;
  int* S      = (int*)w;   w += L4 * 4;
  int* bsum   = (int*)w;   w += nbs4 * 4;
  int* bbase  = (int*)w;   w += nbs4 * 4;
  float* dinv = (float*)w; w += n4 * 4;
  int* off2h  = (int*)w;   w += np4 * 4;
  unsigned short* h1p = (unsigned short*)w;  w += n4 * (size_t)H1 * 2;  // bf16 [n][64]
  unsigned short* h2p = (unsigned short*)w;                             // bf16 [n][32]

  k_hist<<<BLK, 256, 0, stream>>>(dstp, bh, E, EPB, NBk);
  k_gsc1<<<nbs, 256, 0, stream>>>(bh, bsum, L);
  k_gsc2<<<1, 256, 0, stream>>>(bsum, bbase, S, nbs, L);
  k_gsc3<<<nbs, 256, 0, stream>>>(bh, bbase, S, L);
  k_scatter<<<BLK, 256, 0, stream>>>(src, dstp, S, packed, E, EPB, NBk);
  k_build2<<<NBk, 256, 0, stream>>>(packed, S, csr2, off2h, dinv, n, NBk, NT);

  k_proj1<<<(n + 15) / 16, 256, 0, stream>>>((const float4*)x, W1, dinv, h1p, n);
  k_zagg1<<<2 * NBk, 256, 0, stream>>>((const uint4*)h1p, h1p, dinv, S, off2h, csr2,
                                       b1, W2, h2p, n);
  k_zagg2<<<2 * NBk, 256, 0, stream>>>((const uint4*)h2p, h2p, dinv, S, off2h, csr2,
                                       b2, gw, gb, lw, out, n);
}

// Round 4
// 378.269 us; speedup vs baseline: 6.0602x; 6.0602x over previous
//
#include <hip/hip_runtime.h>
#include <math.h>

#define IN_DIM 128
#define H1 64
#define H2 32
#define NC 8
#define SCAN_CH 1024   // elements per scan block (256 threads x 4)
#define NB_MAX 512     // max buckets (n <= 131072)
#define BLK 512        // edge partition blocks
#define CAP 12288      // LDS staging capacity per bucket (entries)

typedef unsigned int u32;

__device__ __forceinline__ float bf_lo(u32 u) { return __uint_as_float(u << 16); }
__device__ __forceinline__ float bf_hi(u32 u) { return __uint_as_float(u & 0xffff0000u); }
__device__ __forceinline__ unsigned short f2b(float f) {  // RNE float->bf16
  u32 u = __float_as_uint(f);
  u += 0x7fffu + ((u >> 16) & 1u);
  return (unsigned short)(u >> 16);
}

// ---------------- P1: per-block bucket histogram (LDS atomics only) ----------------
// bucket(d) = d >> 8 (256 nodes per bucket).

__global__ __launch_bounds__(256) void k_hist(const int* __restrict__ dst,
                                              int* __restrict__ bh,
                                              int E, int EPB, int NBk) {
  __shared__ int h[NB_MAX];
  int k = blockIdx.x, tid = threadIdx.x;
  for (int i = tid; i < NBk; i += 256) h[i] = 0;
  __syncthreads();
  int st = k * EPB, en = min(E, st + EPB);
  for (int i = st + tid; i < en; i += 256)
    atomicAdd(&h[((u32)dst[i]) >> 8], 1);
  __syncthreads();
  for (int b = tid; b < NBk; b += 256) bh[b * BLK + k] = h[b];
}

// ---- generic 3-phase exclusive scan of A[L] -> S[L], S[L] = total ----

__global__ __launch_bounds__(256) void k_gsc1(const int* __restrict__ A,
                                              int* __restrict__ bsum, int L) {
  int b = blockIdx.x, tid = threadIdx.x;
  int i0 = b * SCAN_CH + tid * 4;
  int s = 0;
  if (i0 + 3 < L) {
    int4 v = *(const int4*)(A + i0);
    s = v.x + v.y + v.z + v.w;
  } else {
    for (int i = i0; i < L; ++i) s += A[i];
  }
  __shared__ int red[256];
  red[tid] = s;
  __syncthreads();
  for (int d = 128; d > 0; d >>= 1) {
    if (tid < d) red[tid] += red[tid + d];
    __syncthreads();
  }
  if (tid == 0) bsum[b] = red[0];
}

__global__ __launch_bounds__(256) void k_gsc2(const int* __restrict__ bsum,
                                              int* __restrict__ bbase,
                                              int* __restrict__ S, int nbk, int L) {
  __shared__ int part[256];
  int tid = threadIdx.x;
  int chunk = (nbk + 255) / 256;
  int st = tid * chunk, en = min(st + chunk, nbk);
  int s = 0;
  for (int i = st; i < en; ++i) s += bsum[i];
  part[tid] = s;
  __syncthreads();
  for (int d = 1; d < 256; d <<= 1) {
    int t = (tid >= d) ? part[tid - d] : 0;
    __syncthreads();
    part[tid] += t;
    __syncthreads();
  }
  int base = (tid == 0) ? 0 : part[tid - 1];
  for (int i = st; i < en; ++i) { bbase[i] = base; base += bsum[i]; }
  if (tid == 255) S[L] = part[255];
}

__global__ __launch_bounds__(256) void k_gsc3(const int* __restrict__ A,
                                              const int* __restrict__ bbase,
                                              int* __restrict__ S, int L) {
  int b = blockIdx.x, tid = threadIdx.x;
  int i0 = b * SCAN_CH + tid * 4;
  int e0 = 0, e1 = 0, e2 = 0, e3 = 0;
  if (i0 + 3 < L) {
    int4 v = *(const int4*)(A + i0);
    e0 = v.x; e1 = v.y; e2 = v.z; e3 = v.w;
  } else {
    if (i0 + 0 < L) e0 = A[i0 + 0];
    if (i0 + 1 < L) e1 = A[i0 + 1];
    if (i0 + 2 < L) e2 = A[i0 + 2];
    if (i0 + 3 < L) e3 = A[i0 + 3];
  }
  __shared__ int part[256];
  part[tid] = e0 + e1 + e2 + e3;
  __syncthreads();
  for (int d = 1; d < 256; d <<= 1) {
    int t = (tid >= d) ? part[tid - d] : 0;
    __syncthreads();
    part[tid] += t;
    __syncthreads();
  }
  int base = bbase[b] + ((tid == 0) ? 0 : part[tid - 1]);
  int o0 = base, o1 = o0 + e0, o2 = o1 + e1, o3 = o2 + e2;
  if (i0 + 3 < L) {
    int4 o; o.x = o0; o.y = o1; o.z = o2; o.w = o3;
    *(int4*)(S + i0) = o;
  } else {
    if (i0 + 0 < L) S[i0 + 0] = o0;
    if (i0 + 1 < L) S[i0 + 1] = o1;
    if (i0 + 2 < L) S[i0 + 2] = o2;
    if (i0 + 3 < L) S[i0 + 3] = o3;
  }
}

// ---------------- P3: bucket scatter (LDS cursors, disjoint global ranges) ----------------
// packed entry: bits[0,17) = src, bits[17,25) = local node id within bucket.

__global__ __launch_bounds__(256) void k_scatter(const int* __restrict__ src,
                                                 const int* __restrict__ dst,
                                                 const int* __restrict__ S,
                                                 u32* __restrict__ packed,
                                                 int E, int EPB, int NBk) {
  __shared__ int cur[NB_MAX];
  int k = blockIdx.x, tid = threadIdx.x;
  for (int b = tid; b < NBk; b += 256) cur[b] = S[b * BLK + k];
  __syncthreads();
  int st = k * EPB, en = min(E, st + EPB);
  for (int i = st + tid; i < en; i += 256) {
    int d = dst[i];
    int b = ((u32)d) >> 8;
    int pos = atomicAdd(&cur[b], 1);
    packed[pos] = (((u32)d & 255u) << 17) | (u32)src[i];
  }
}

// ---------------- P4: per-bucket CSR build + off + dinv ----------------

__global__ __launch_bounds__(256) void k_build(const u32* __restrict__ packed,
                                               const int* __restrict__ S,
                                               int* __restrict__ csr,
                                               int* __restrict__ off,
                                               float* __restrict__ dinv,
                                               int n, int NBk) {
  __shared__ int cnt[256];
  __shared__ int tmp[256];
  __shared__ int cur[256];
  __shared__ int sbuf[CAP];  // 48 KB staging
  int b = blockIdx.x, tid = threadIdx.x;
  int r0 = S[b * BLK];
  int r1 = S[(b + 1) * BLK];  // for last bucket: S[L] = E
  int m = r1 - r0;
  cnt[tid] = 0;
  __syncthreads();
  for (int i = r0 + tid; i < r1; i += 256)
    atomicAdd(&cnt[packed[i] >> 17], 1);
  __syncthreads();
  int v = cnt[tid];
  tmp[tid] = v;
  __syncthreads();
  for (int d = 1; d < 256; d <<= 1) {
    int t = (tid >= d) ? tmp[tid - d] : 0;
    __syncthreads();
    tmp[tid] += t;
    __syncthreads();
  }
  int rel = tmp[tid] - v;  // exclusive prefix within bucket
  int node = b * 256 + tid;
  if (node < n) {
    off[node] = r0 + rel;
    dinv[node] = rsqrtf((float)(v + 1));  // +1 self-loop
  }
  if (b == NBk - 1 && tid == 0) off[n] = r1;
  cur[tid] = rel;
  __syncthreads();
  if (m <= CAP) {
    for (int i = r0 + tid; i < r1; i += 256) {
      u32 u = packed[i];
      int pos = atomicAdd(&cur[u >> 17], 1);
      sbuf[pos] = (int)(u & 0x1FFFFu);
    }
    __syncthreads();
    for (int j = tid; j < m; j += 256)
      csr[r0 + j] = sbuf[j];
  } else {
    for (int i = r0 + tid; i < r1; i += 256) {
      u32 u = packed[i];
      int pos = atomicAdd(&cur[u >> 17], 1);
      csr[r0 + pos] = (int)(u & 0x1FFFFu);
    }
  }
}

// ---------------- projection 1: h1p = bf16(dinv * (x @ W1^T))  [n,128]->[n,64] ----------------

__global__ void k_proj1(const float4* __restrict__ x4, const float* __restrict__ W1,
                        const float* __restrict__ dinv,
                        unsigned short* __restrict__ h1p, int n) {
  __shared__ float xs[16][IN_DIM];
  __shared__ float wt[IN_DIM][H1 + 1];
  int tid = threadIdx.x;
  int row0 = blockIdx.x * 16;

  for (int i = tid; i < (H1 * IN_DIM / 4); i += 256) {
    float4 w = ((const float4*)W1)[i];
    int o = (i * 4) / IN_DIM;
    int k = (i * 4) % IN_DIM;
    wt[k + 0][o] = w.x; wt[k + 1][o] = w.y; wt[k + 2][o] = w.z; wt[k + 3][o] = w.w;
  }
  for (int i = tid; i < 16 * IN_DIM / 4; i += 256) {
    int r = (i * 4) / IN_DIM, k = (i * 4) % IN_DIM;
    int row = row0 + r;
    if (row < n)
      *((float4*)&xs[r][k]) = x4[(size_t)row * (IN_DIM / 4) + k / 4];
  }
  __syncthreads();

  int o = tid & 63, rq = tid >> 6;
  float a0 = 0.f, a1 = 0.f, a2 = 0.f, a3 = 0.f;
  for (int k = 0; k < IN_DIM; ++k) {
    float w = wt[k][o];
    a0 += xs[rq * 4 + 0][k] * w;
    a1 += xs[rq * 4 + 1][k] * w;
    a2 += xs[rq * 4 + 2][k] * w;
    a3 += xs[rq * 4 + 3][k] * w;
  }
  int r = row0 + rq * 4;
  if (r + 0 < n) h1p[(size_t)(r + 0) * H1 + o] = f2b(a0 * dinv[r + 0]);
  if (r + 1 < n) h1p[(size_t)(r + 1) * H1 + o] = f2b(a1 * dinv[r + 1]);
  if (r + 2 < n) h1p[(size_t)(r + 2) * H1 + o] = f2b(a2 * dinv[r + 2]);
  if (r + 3 < n) h1p[(size_t)(r + 3) * H1 + o] = f2b(a3 * dinv[r + 3]);
}

// ---------------- fused: layer-1 gather-agg + bias + relu + proj2 ----------------
// R17: reverted to R1 structure (best measured). Workspace now 256B-aligned so
// each 128B h1p row is exactly one cache line (was offset 80 mod 128 -> straddle).

#define ACC8(v) do { \
    a0 += bf_lo((v).x); a1 += bf_hi((v).x); \
    a2 += bf_lo((v).y); a3 += bf_hi((v).y); \
    a4 += bf_lo((v).z); a5 += bf_hi((v).z); \
    a6 += bf_lo((v).w); a7 += bf_hi((v).w); } while (0)

#define RED8(m) do { \
    a0 += __shfl_xor(a0, m, 64); a1 += __shfl_xor(a1, m, 64); \
    a2 += __shfl_xor(a2, m, 64); a3 += __shfl_xor(a3, m, 64); \
    a4 += __shfl_xor(a4, m, 64); a5 += __shfl_xor(a5, m, 64); \
    a6 += __shfl_xor(a6, m, 64); a7 += __shfl_xor(a7, m, 64); } while (0)

__global__ __launch_bounds__(256) void k_agg64_proj2(
    const u32* __restrict__ hp,    // [n][32] packed bf16x2 (= [n][8] uint4)
    const float* __restrict__ dinv,
    const int* __restrict__ off, const int* __restrict__ csr,
    const float* __restrict__ b1, const float* __restrict__ W2,
    unsigned short* __restrict__ h2p, int n) {
  __shared__ float wt[H1][H2 + 1];   // W2 transposed: wt[k][o]
  __shared__ float rows[4][H1];      // relu(out1) row per wave
  __shared__ float b1s[H1];
  int tid = threadIdx.x;

  for (int i = tid; i < H2 * H1 / 4; i += 256) {
    float4 w = ((const float4*)W2)[i];
    int o = (i * 4) / H1, k = (i * 4) % H1;
    wt[k + 0][o] = w.x; wt[k + 1][o] = w.y; wt[k + 2][o] = w.z; wt[k + 3][o] = w.w;
  }
  if (tid < 16) ((float4*)b1s)[tid] = ((const float4*)b1)[tid];
  __syncthreads();   // b1s is read before the rows-barrier, so sync staging here

  int lane = tid & 63;
  int wv = __builtin_amdgcn_readfirstlane(tid >> 6);
  int wid0 = blockIdx.x * 4 + wv;
  int wid = wid0 < n ? wid0 : n - 1;   // clamp so all waves reach barriers
  int g = lane >> 3, j = lane & 7;     // 8 groups of 8 lanes; lane j reads 16B

  const uint4* __restrict__ hp4 = (const uint4*)hp;
  float a0 = 0.f, a1 = 0.f, a2 = 0.f, a3 = 0.f,
        a4 = 0.f, a5 = 0.f, a6 = 0.f, a7 = 0.f;

  if (g == 0) {  // self term (table already has dinv[self] folded in)
    uint4 v = hp4[(size_t)wid * (H1 / 8) + j];
    ACC8(v);
  }
  int r0 = off[wid], r1 = off[wid + 1];
  for (int base = r0; base < r1; base += 32) {
    int ci = base + (lane & 31);
    int s = csr[min(ci, r1 - 1)];      // clamped coalesced load of 32 src ids
#pragma unroll
    for (int it = 0; it < 4; ++it) {
      int sv = __shfl(s, it * 8 + g, 64);     // distribute src to group g
      if (base + it * 8 + g < r1) {
        uint4 v = hp4[(size_t)sv * (H1 / 8) + j];   // 8 edges / instruction
        ACC8(v);
      }
    }
  }
  RED8(8); RED8(16); RED8(32);  // reduce across the 8 groups

  float d = dinv[wid];
  if (lane < 8) {   // lane j holds cols [8j, 8j+8)
    float4 v0, v1;
    v0.x = fmaxf(a0 * d + b1s[8 * lane + 0], 0.f);
    v0.y = fmaxf(a1 * d + b1s[8 * lane + 1], 0.f);
    v0.z = fmaxf(a2 * d + b1s[8 * lane + 2], 0.f);
    v0.w = fmaxf(a3 * d + b1s[8 * lane + 3], 0.f);
    v1.x = fmaxf(a4 * d + b1s[8 * lane + 4], 0.f);
    v1.y = fmaxf(a5 * d + b1s[8 * lane + 5], 0.f);
    v1.z = fmaxf(a6 * d + b1s[8 * lane + 6], 0.f);
    v1.w = fmaxf(a7 * d + b1s[8 * lane + 7], 0.f);
    *(float4*)&rows[wv][8 * lane + 0] = v0;
    *(float4*)&rows[wv][8 * lane + 4] = v1;
  }
  __syncthreads();

  // proj2: half-wave split over k, 32 outputs per node
  int half = lane >> 5, o = lane & 31;
  float a = 0.f;
#pragma unroll
  for (int k = 0; k < 32; ++k) {
    int kk = half * 32 + k;
    a += rows[wv][kk] * wt[kk][o];
  }
  a += __shfl_down(a, 32, 64);
  if (half == 0 && wid0 < n) h2p[(size_t)wid0 * H2 + o] = f2b(a * d);
}

// ---------------- fused: layer-2 gather-agg + b2 + gates + leaf ----------------
// dwordx4 gathers: 4 lanes/edge => 16 edges per wave VMEM instruction.

__global__ __launch_bounds__(256) void k_agg32_tree(
    const u32* __restrict__ hp,    // [n][16] packed bf16x2 (= [n][4] uint4)
    const float* __restrict__ dinv,
    const int* __restrict__ off, const int* __restrict__ csr,
    const float* __restrict__ b2, const float* __restrict__ gate_w,
    const float* __restrict__ gate_b, const float* __restrict__ leaf_w,
    float* __restrict__ out, int n) {
  __shared__ float gwt[H2][H2 + 1];  // gate_w transposed: gwt[k][j]
  __shared__ float lws[H2][NC + 1];
  __shared__ float rowh[4][H2];
  __shared__ float rowg[4][H2];
  __shared__ float b2s[H2];
  int tid = threadIdx.x;

  {
    float4 w = ((const float4*)gate_w)[tid];  // H2*H2/4 == 256
    int jj = (tid * 4) / H2, k = (tid * 4) % H2;
    gwt[k + 0][jj] = w.x; gwt[k + 1][jj] = w.y; gwt[k + 2][jj] = w.z; gwt[k + 3][jj] = w.w;
  }
  lws[tid >> 3][tid & 7] = leaf_w[tid];  // H2*NC == 256
  if (tid < 8) ((float4*)b2s)[tid] = ((const float4*)b2)[tid];
  __syncthreads();   // b2s read before the rowh-barrier

  int lane = tid & 63;
  int wv = __builtin_amdgcn_readfirstlane(tid >> 6);
  int wid0 = blockIdx.x * 4 + wv;
  int wid = wid0 < n ? wid0 : n - 1;
  int g = lane >> 2, j = lane & 3;   // 16 groups of 4 lanes; lane j reads 16B

  const uint4* __restrict__ hp4 = (const uint4*)hp;
  float a0 = 0.f, a1 = 0.f, a2 = 0.f, a3 = 0.f,
        a4 = 0.f, a5 = 0.f, a6 = 0.f, a7 = 0.f;

  if (g == 0) {  // self term
    uint4 v = hp4[(size_t)wid * (H2 / 8) + j];
    ACC8(v);
  }
  int r0 = off[wid], r1 = off[wid + 1];
  for (int base = r0; base < r1; base += 32) {
    int ci = base + (lane & 31);
    int s = csr[min(ci, r1 - 1)];
#pragma unroll
    for (int it = 0; it < 2; ++it) {
      int sv = __shfl(s, it * 16 + g, 64);
      if (base + it * 16 + g < r1) {
        uint4 v = hp4[(size_t)sv * (H2 / 8) + j];   // 16 edges / instruction
        ACC8(v);
      }
    }
  }
  RED8(4); RED8(8); RED8(16); RED8(32);  // reduce across the 16 groups

  float d = dinv[wid];
  if (lane < 4) {   // lane j holds cols [8j, 8j+8)
    float4 v0, v1;
    v0.x = a0 * d + b2s[8 * lane + 0];
    v0.y = a1 * d + b2s[8 * lane + 1];
    v0.z = a2 * d + b2s[8 * lane + 2];
    v0.w = a3 * d + b2s[8 * lane + 3];
    v1.x = a4 * d + b2s[8 * lane + 4];
    v1.y = a5 * d + b2s[8 * lane + 5];
    v1.z = a6 * d + b2s[8 * lane + 6];
    v1.w = a7 * d + b2s[8 * lane + 7];
    *(float4*)&rowh[wv][8 * lane + 0] = v0;
    *(float4*)&rowh[wv][8 * lane + 4] = v1;
  }
  __syncthreads();

  // gates: j = f, half-wave split over k (16 each)
  int half = lane >> 5, f = lane & 31;
  float gacc = 0.f;
#pragma unroll
  for (int k = 0; k < 16; ++k) {
    int kk = half * 16 + k;
    gacc += rowh[wv][kk] * gwt[kk][f];
  }
  gacc += __shfl_down(gacc, 32, 64);
  if (half == 0) rowg[wv][f] = 1.0f / (1.0f + __expf(-(gacc + gate_b[f])));
  __syncthreads();

  // leaf: 8 groups of 8 lanes
  int c = lane & 7, gi = lane >> 3;
  float a = 0.f;
#pragma unroll
  for (int j4 = 0; j4 < 4; ++j4) {
    int jj = gi * 4 + j4;
    a += rowg[wv][jj] * lws[jj][c];
  }
  a += __shfl_down(a, 32, 64);
  a += __shfl_down(a, 16, 64);
  a += __shfl_down(a, 8, 64);
  if (lane < 8 && wid0 < n) out[(size_t)wid0 * NC + lane] = a;
}

// ---------------- host ----------------

static inline size_t align256(size_t x) { return (x + 255) & ~(size_t)255; }

extern "C" void kernel_launch(void* const* d_in, const int* in_sizes, int n_in,
                              void* d_out, int out_size, void* d_ws, size_t ws_size,
                              hipStream_t stream) {
  const float* x  = (const float*)d_in[0];
  const int*   ei = (const int*)d_in[1];
  const float* W1 = (const float*)d_in[2];
  const float* b1 = (const float*)d_in[3];
  const float* W2 = (const float*)d_in[4];
  const float* b2 = (const float*)d_in[5];
  const float* gw = (const float*)d_in[6];
  const float* gb = (const float*)d_in[7];
  const float* lw = (const float*)d_in[8];
  float* out = (float*)d_out;

  int n = in_sizes[0] / IN_DIM;
  int E = in_sizes[1] / 2;
  const int* src  = ei;
  const int* dstp = ei + E;

  int NBk = (n + 255) >> 8;                    // buckets of 256 nodes
  int EPB = (E + BLK - 1) / BLK;               // edges per partition block
  int L   = NBk * BLK;                         // blockhist entries
  int nbs = (L + SCAN_CH - 1) / SCAN_CH;       // scan blocks

  // workspace layout: hot gather tables FIRST (256B-aligned => each h1p row is
  // exactly one 128B line, each h2p row one 64B sector; R17 straddle fix),
  // then every chunk rounded to 256B.
  char* w = (char*)d_ws;
  unsigned short* h1p = (unsigned short*)w;  w += align256((size_t)n * H1 * 2);  // bf16 [n][64]
  unsigned short* h2p = (unsigned short*)w;  w += align256((size_t)n * H2 * 2);  // bf16 [n][32]
  int* csr    = (int*)w;   w += align256((size_t)E * 4);
  u32* packed = (u32*)w;   w += align256((size_t)E * 4);
  int* bh     = (int*)w;   w += align256(((size_t)L + 1) * 4);
  int* S      = (int*)w;   w += align256(((size_t)L + 1) * 4);
  int* bsum   = (int*)w;   w += align256((size_t)nbs * 4);
  int* bbase  = (int*)w;   w += align256((size_t)nbs * 4);
  float* dinv = (float*)w; w += align256((size_t)n * 4);
  int* off    = (int*)w;   w += align256(((size_t)n + 1) * 4);

  int gw4 = (n + 3) / 4;  // 4 nodes per 256-thread block

  k_hist<<<BLK, 256, 0, stream>>>(dstp, bh, E, EPB, NBk);
  k_gsc1<<<nbs, 256, 0, stream>>>(bh, bsum, L);
  k_gsc2<<<1, 256, 0, stream>>>(bsum, bbase, S, nbs, L);
  k_gsc3<<<nbs, 256, 0, stream>>>(bh, bbase, S, L);
  k_scatter<<<BLK, 256, 0, stream>>>(src, dstp, S, packed, E, EPB, NBk);
  k_build<<<NBk, 256, 0, stream>>>(packed, S, csr, off, dinv, n, NBk);

  k_proj1<<<(n + 15) / 16, 256, 0, stream>>>((const float4*)x, W1, dinv, h1p, n);
  k_agg64_proj2<<<gw4, 256, 0, stream>>>((const u32*)h1p, dinv, off, csr, b1, W2, h2p, n);
  k_agg32_tree<<<gw4, 256, 0, stream>>>((const u32*)h2p, dinv, off, csr, b2, gw, gb, lw, out, n);
}

// Round 5
// 350.856 us; speedup vs baseline: 6.5337x; 1.0781x over previous
//
#include <hip/hip_runtime.h>
#include <math.h>

#define IN_DIM 128
#define H1 64
#define H2 32
#define NC 8
#define SCAN_CH 1024   // elements per scan block (256 threads x 4)
#define NB_MAX 512     // max buckets (n <= 131072)
#define BLK 512        // edge partition blocks
#define CAP 12288      // LDS staging capacity per bucket (entries)

typedef unsigned int u32;

__device__ __forceinline__ float bf_lo(u32 u) { return __uint_as_float(u << 16); }
__device__ __forceinline__ float bf_hi(u32 u) { return __uint_as_float(u & 0xffff0000u); }
__device__ __forceinline__ unsigned short f2b(float f) {  // RNE float->bf16
  u32 u = __float_as_uint(f);
  u += 0x7fffu + ((u >> 16) & 1u);
  return (unsigned short)(u >> 16);
}

// ---------------- P1: per-block bucket histogram (LDS atomics only) ----------------
// bucket(d) = d >> 8 (256 nodes per bucket).

__global__ __launch_bounds__(256) void k_hist(const int* __restrict__ dst,
                                              int* __restrict__ bh,
                                              int E, int EPB, int NBk) {
  __shared__ int h[NB_MAX];
  int k = blockIdx.x, tid = threadIdx.x;
  for (int i = tid; i < NBk; i += 256) h[i] = 0;
  __syncthreads();
  int st = k * EPB, en = min(E, st + EPB);
  for (int i = st + tid; i < en; i += 256)
    atomicAdd(&h[((u32)dst[i]) >> 8], 1);
  __syncthreads();
  for (int b = tid; b < NBk; b += 256) bh[b * BLK + k] = h[b];
}

// ---- generic 3-phase exclusive scan of A[L] -> S[L], S[L] = total ----

__global__ __launch_bounds__(256) void k_gsc1(const int* __restrict__ A,
                                              int* __restrict__ bsum, int L) {
  int b = blockIdx.x, tid = threadIdx.x;
  int i0 = b * SCAN_CH + tid * 4;
  int s = 0;
  if (i0 + 3 < L) {
    int4 v = *(const int4*)(A + i0);
    s = v.x + v.y + v.z + v.w;
  } else {
    for (int i = i0; i < L; ++i) s += A[i];
  }
  __shared__ int red[256];
  red[tid] = s;
  __syncthreads();
  for (int d = 128; d > 0; d >>= 1) {
    if (tid < d) red[tid] += red[tid + d];
    __syncthreads();
  }
  if (tid == 0) bsum[b] = red[0];
}

__global__ __launch_bounds__(256) void k_gsc2(const int* __restrict__ bsum,
                                              int* __restrict__ bbase,
                                              int* __restrict__ S, int nbk, int L) {
  __shared__ int part[256];
  int tid = threadIdx.x;
  int chunk = (nbk + 255) / 256;
  int st = tid * chunk, en = min(st + chunk, nbk);
  int s = 0;
  for (int i = st; i < en; ++i) s += bsum[i];
  part[tid] = s;
  __syncthreads();
  for (int d = 1; d < 256; d <<= 1) {
    int t = (tid >= d) ? part[tid - d] : 0;
    __syncthreads();
    part[tid] += t;
    __syncthreads();
  }
  int base = (tid == 0) ? 0 : part[tid - 1];
  for (int i = st; i < en; ++i) { bbase[i] = base; base += bsum[i]; }
  if (tid == 255) S[L] = part[255];
}

__global__ __launch_bounds__(256) void k_gsc3(const int* __restrict__ A,
                                              const int* __restrict__ bbase,
                                              int* __restrict__ S, int L) {
  int b = blockIdx.x, tid = threadIdx.x;
  int i0 = b * SCAN_CH + tid * 4;
  int e0 = 0, e1 = 0, e2 = 0, e3 = 0;
  if (i0 + 3 < L) {
    int4 v = *(const int4*)(A + i0);
    e0 = v.x; e1 = v.y; e2 = v.z; e3 = v.w;
  } else {
    if (i0 + 0 < L) e0 = A[i0 + 0];
    if (i0 + 1 < L) e1 = A[i0 + 1];
    if (i0 + 2 < L) e2 = A[i0 + 2];
    if (i0 + 3 < L) e3 = A[i0 + 3];
  }
  __shared__ int part[256];
  part[tid] = e0 + e1 + e2 + e3;
  __syncthreads();
  for (int d = 1; d < 256; d <<= 1) {
    int t = (tid >= d) ? part[tid - d] : 0;
    __syncthreads();
    part[tid] += t;
    __syncthreads();
  }
  int base = bbase[b] + ((tid == 0) ? 0 : part[tid - 1]);
  int o0 = base, o1 = o0 + e0, o2 = o1 + e1, o3 = o2 + e2;
  if (i0 + 3 < L) {
    int4 o; o.x = o0; o.y = o1; o.z = o2; o.w = o3;
    *(int4*)(S + i0) = o;
  } else {
    if (i0 + 0 < L) S[i0 + 0] = o0;
    if (i0 + 1 < L) S[i0 + 1] = o1;
    if (i0 + 2 < L) S[i0 + 2] = o2;
    if (i0 + 3 < L) S[i0 + 3] = o3;
  }
}

// ---------------- P3: bucket scatter (LDS cursors, disjoint global ranges) ----------------
// packed entry: bits[0,17) = src, bits[17,25) = local node id within bucket.

__global__ __launch_bounds__(256) void k_scatter(const int* __restrict__ src,
                                                 const int* __restrict__ dst,
                                                 const int* __restrict__ S,
                                                 u32* __restrict__ packed,
                                                 int E, int EPB, int NBk) {
  __shared__ int cur[NB_MAX];
  int k = blockIdx.x, tid = threadIdx.x;
  for (int b = tid; b < NBk; b += 256) cur[b] = S[b * BLK + k];
  __syncthreads();
  int st = k * EPB, en = min(E, st + EPB);
  for (int i = st + tid; i < en; i += 256) {
    int d = dst[i];
    int b = ((u32)d) >> 8;
    int pos = atomicAdd(&cur[b], 1);
    packed[pos] = (((u32)d & 255u) << 17) | (u32)src[i];
  }
}

// ---------------- P4: per-bucket CSR build + off + dinv ----------------

__global__ __launch_bounds__(256) void k_build(const u32* __restrict__ packed,
                                               const int* __restrict__ S,
                                               int* __restrict__ csr,
                                               int* __restrict__ off,
                                               float* __restrict__ dinv,
                                               int n, int NBk) {
  __shared__ int cnt[256];
  __shared__ int tmp[256];
  __shared__ int cur[256];
  __shared__ int sbuf[CAP];  // 48 KB staging
  int b = blockIdx.x, tid = threadIdx.x;
  int r0 = S[b * BLK];
  int r1 = S[(b + 1) * BLK];  // for last bucket: S[L] = E
  int m = r1 - r0;
  cnt[tid] = 0;
  __syncthreads();
  for (int i = r0 + tid; i < r1; i += 256)
    atomicAdd(&cnt[packed[i] >> 17], 1);
  __syncthreads();
  int v = cnt[tid];
  tmp[tid] = v;
  __syncthreads();
  for (int d = 1; d < 256; d <<= 1) {
    int t = (tid >= d) ? tmp[tid - d] : 0;
    __syncthreads();
    tmp[tid] += t;
    __syncthreads();
  }
  int rel = tmp[tid] - v;  // exclusive prefix within bucket
  int node = b * 256 + tid;
  if (node < n) {
    off[node] = r0 + rel;
    dinv[node] = rsqrtf((float)(v + 1));  // +1 self-loop
  }
  if (b == NBk - 1 && tid == 0) off[n] = r1;
  cur[tid] = rel;
  __syncthreads();
  if (m <= CAP) {
    for (int i = r0 + tid; i < r1; i += 256) {
      u32 u = packed[i];
      int pos = atomicAdd(&cur[u >> 17], 1);
      sbuf[pos] = (int)(u & 0x1FFFFu);
    }
    __syncthreads();
    for (int j = tid; j < m; j += 256)
      csr[r0 + j] = sbuf[j];
  } else {
    for (int i = r0 + tid; i < r1; i += 256) {
      u32 u = packed[i];
      int pos = atomicAdd(&cur[u >> 17], 1);
      csr[r0 + pos] = (int)(u & 0x1FFFFu);
    }
  }
}

// ---------------- projection 1: h1p = bf16(dinv * (x @ W1^T))  [n,128]->[n,64] ----------------

__global__ void k_proj1(const float4* __restrict__ x4, const float* __restrict__ W1,
                        const float* __restrict__ dinv,
                        unsigned short* __restrict__ h1p, int n) {
  __shared__ float xs[16][IN_DIM];
  __shared__ float wt[IN_DIM][H1 + 1];
  int tid = threadIdx.x;
  int row0 = blockIdx.x * 16;

  for (int i = tid; i < (H1 * IN_DIM / 4); i += 256) {
    float4 w = ((const float4*)W1)[i];
    int o = (i * 4) / IN_DIM;
    int k = (i * 4) % IN_DIM;
    wt[k + 0][o] = w.x; wt[k + 1][o] = w.y; wt[k + 2][o] = w.z; wt[k + 3][o] = w.w;
  }
  for (int i = tid; i < 16 * IN_DIM / 4; i += 256) {
    int r = (i * 4) / IN_DIM, k = (i * 4) % IN_DIM;
    int row = row0 + r;
    if (row < n)
      *((float4*)&xs[r][k]) = x4[(size_t)row * (IN_DIM / 4) + k / 4];
  }
  __syncthreads();

  int o = tid & 63, rq = tid >> 6;
  float a0 = 0.f, a1 = 0.f, a2 = 0.f, a3 = 0.f;
  for (int k = 0; k < IN_DIM; ++k) {
    float w = wt[k][o];
    a0 += xs[rq * 4 + 0][k] * w;
    a1 += xs[rq * 4 + 1][k] * w;
    a2 += xs[rq * 4 + 2][k] * w;
    a3 += xs[rq * 4 + 3][k] * w;
  }
  int r = row0 + rq * 4;
  if (r + 0 < n) h1p[(size_t)(r + 0) * H1 + o] = f2b(a0 * dinv[r + 0]);
  if (r + 1 < n) h1p[(size_t)(r + 1) * H1 + o] = f2b(a1 * dinv[r + 1]);
  if (r + 2 < n) h1p[(size_t)(r + 2) * H1 + o] = f2b(a2 * dinv[r + 2]);
  if (r + 3 < n) h1p[(size_t)(r + 3) * H1 + o] = f2b(a3 * dinv[r + 3]);
}

// ---------------- fused: layer-1 gather-agg + bias + relu + proj2 ----------------
// R18: TWO independent nodes per wave (latency-chain theory). Per k-step: one
// csr load carries 16 ids per node (lanes 0-15 / 32-47); each of the 4 gather
// instrs carries 4 edges of node0 (groups 0-3) + 4 of node1 (groups 4-7).
// Same 8-rows-per-instruction efficiency, 2x independent chains per wave slot.

#define ACC8(v) do { \
    a0 += bf_lo((v).x); a1 += bf_hi((v).x); \
    a2 += bf_lo((v).y); a3 += bf_hi((v).y); \
    a4 += bf_lo((v).z); a5 += bf_hi((v).z); \
    a6 += bf_lo((v).w); a7 += bf_hi((v).w); } while (0)

#define RED8(m) do { \
    a0 += __shfl_xor(a0, m, 64); a1 += __shfl_xor(a1, m, 64); \
    a2 += __shfl_xor(a2, m, 64); a3 += __shfl_xor(a3, m, 64); \
    a4 += __shfl_xor(a4, m, 64); a5 += __shfl_xor(a5, m, 64); \
    a6 += __shfl_xor(a6, m, 64); a7 += __shfl_xor(a7, m, 64); } while (0)

__global__ __launch_bounds__(256) void k_agg64_proj2(
    const u32* __restrict__ hp,    // [n][32] packed bf16x2 (= [n][8] uint4)
    const float* __restrict__ dinv,
    const int* __restrict__ off, const int* __restrict__ csr,
    const float* __restrict__ b1, const float* __restrict__ W2,
    unsigned short* __restrict__ h2p, int n) {
  __shared__ float wt[H1][H2 + 1];   // W2 transposed: wt[k][o]
  __shared__ float rows[4][2][H1];   // relu(out1) rows, 2 nodes per wave
  __shared__ float b1s[H1];
  int tid = threadIdx.x;

  for (int i = tid; i < H2 * H1 / 4; i += 256) {
    float4 w = ((const float4*)W2)[i];
    int o = (i * 4) / H1, k = (i * 4) % H1;
    wt[k + 0][o] = w.x; wt[k + 1][o] = w.y; wt[k + 2][o] = w.z; wt[k + 3][o] = w.w;
  }
  if (tid < 16) ((float4*)b1s)[tid] = ((const float4*)b1)[tid];
  __syncthreads();

  int lane = tid & 63;
  int wv = __builtin_amdgcn_readfirstlane(tid >> 6);
  int p0n = (blockIdx.x * 4 + wv) * 2;       // first of this wave's 2 nodes
  int p0c = min(p0n, n - 1);
  int p1c = min(p0n + 1, n - 1);
  int g = lane >> 3, j = lane & 7;           // 8 groups of 8 lanes; lane j reads 16B
  int nh = g >> 2;                           // node-half of this group

  // off[p0n .. p0n+2] via one load + shfl (wave-uniform ranges)
  int tt = 0;
  if (lane < 3) tt = off[min(p0n + lane, n)];
  int r00 = __shfl(tt, 0, 64);
  int r01 = __shfl(tt, 1, 64);
  int r11 = __shfl(tt, 2, 64);
  float dv = 0.f;
  if (lane < 2) dv = dinv[min(p0n + lane, n - 1)];
  float d0 = __shfl(dv, 0, 64), d1 = __shfl(dv, 1, 64);

  const uint4* __restrict__ hp4 = (const uint4*)hp;
  float a0 = 0.f, a1 = 0.f, a2 = 0.f, a3 = 0.f,
        a4 = 0.f, a5 = 0.f, a6 = 0.f, a7 = 0.f;

  if ((g & 3) == 0) {  // self terms: group 0 -> node0, group 4 -> node1
    uint4 v = hp4[(size_t)(nh ? p1c : p0c) * (H1 / 8) + j];
    ACC8(v);
  }

  int mx = max(r01 - r00, r11 - r01);
  for (int kk = 0; kk * 16 < mx; ++kk) {
    int b0 = r00 + 16 * kk, b1e = r01 + 16 * kk;
    int ci = (lane < 32) ? min(b0 + (lane & 15), r01 - 1)
                         : min(b1e + (lane & 15), r11 - 1);
    int s = csr[max(ci, 0)];     // 16 ids per node, clamped coalesced load
#pragma unroll
    for (int it = 0; it < 4; ++it) {
      int e = it * 4 + (g & 3);
      int sv = __shfl(s, (nh ? 32 : 0) + e, 64);
      int eidx = (nh ? b1e : b0) + e;
      int lim = nh ? r11 : r01;
      if (eidx < lim) {
        uint4 v = hp4[(size_t)sv * (H1 / 8) + j];   // 4+4 edges / instruction
        ACC8(v);
      }
    }
  }
  RED8(8); RED8(16);  // reduce across the 4 groups of each node-half

  float d = (lane < 32) ? d0 : d1;
  if ((lane & 31) < 8) {   // lane j holds cols [8j, 8j+8) of its node
    int jj = lane & 7, nn = lane >> 5;
    float4 v0, v1;
    v0.x = fmaxf(a0 * d + b1s[8 * jj + 0], 0.f);
    v0.y = fmaxf(a1 * d + b1s[8 * jj + 1], 0.f);
    v0.z = fmaxf(a2 * d + b1s[8 * jj + 2], 0.f);
    v0.w = fmaxf(a3 * d + b1s[8 * jj + 3], 0.f);
    v1.x = fmaxf(a4 * d + b1s[8 * jj + 4], 0.f);
    v1.y = fmaxf(a5 * d + b1s[8 * jj + 5], 0.f);
    v1.z = fmaxf(a6 * d + b1s[8 * jj + 6], 0.f);
    v1.w = fmaxf(a7 * d + b1s[8 * jj + 7], 0.f);
    *(float4*)&rows[wv][nn][8 * jj + 0] = v0;
    *(float4*)&rows[wv][nn][8 * jj + 4] = v1;
  }
  __syncthreads();

  // proj2: lane -> (node = lane>>5, o = lane&31); full k loop, no final shfl
  int node = lane >> 5, o = lane & 31;
  float a = 0.f;
#pragma unroll
  for (int k = 0; k < H1; ++k) a += rows[wv][node][k] * wt[k][o];
  int wout = p0n + node;
  if (wout < n) h2p[(size_t)wout * H2 + o] = f2b(a * ((node) ? d1 : d0));
}

// ---------------- fused: layer-2 gather-agg + b2 + gates + leaf ----------------
// R18: two nodes per wave; groups 0-7 node0, 8-15 node1 (4 lanes x 16B per edge).

__global__ __launch_bounds__(256) void k_agg32_tree(
    const u32* __restrict__ hp,    // [n][16] packed bf16x2 (= [n][4] uint4)
    const float* __restrict__ dinv,
    const int* __restrict__ off, const int* __restrict__ csr,
    const float* __restrict__ b2, const float* __restrict__ gate_w,
    const float* __restrict__ gate_b, const float* __restrict__ leaf_w,
    float* __restrict__ out, int n) {
  __shared__ float gwt[H2][H2 + 1];  // gate_w transposed: gwt[k][j]
  __shared__ float lws[H2][NC + 1];
  __shared__ float rowh[4][2][H2];
  __shared__ float rowg[4][2][H2];
  __shared__ float b2s[H2];
  int tid = threadIdx.x;

  {
    float4 w = ((const float4*)gate_w)[tid];  // H2*H2/4 == 256
    int jj = (tid * 4) / H2, k = (tid * 4) % H2;
    gwt[k + 0][jj] = w.x; gwt[k + 1][jj] = w.y; gwt[k + 2][jj] = w.z; gwt[k + 3][jj] = w.w;
  }
  lws[tid >> 3][tid & 7] = leaf_w[tid];  // H2*NC == 256
  if (tid < 8) ((float4*)b2s)[tid] = ((const float4*)b2)[tid];
  __syncthreads();

  int lane = tid & 63;
  int wv = __builtin_amdgcn_readfirstlane(tid >> 6);
  int p0n = (blockIdx.x * 4 + wv) * 2;
  int p0c = min(p0n, n - 1);
  int p1c = min(p0n + 1, n - 1);
  int g = lane >> 2, j = lane & 3;   // 16 groups of 4 lanes
  int nh = g >> 3;                   // node-half of this group

  int tt = 0;
  if (lane < 3) tt = off[min(p0n + lane, n)];
  int r00 = __shfl(tt, 0, 64);
  int r01 = __shfl(tt, 1, 64);
  int r11 = __shfl(tt, 2, 64);
  float dv = 0.f;
  if (lane < 2) dv = dinv[min(p0n + lane, n - 1)];
  float d0 = __shfl(dv, 0, 64), d1 = __shfl(dv, 1, 64);

  const uint4* __restrict__ hp4 = (const uint4*)hp;
  float a0 = 0.f, a1 = 0.f, a2 = 0.f, a3 = 0.f,
        a4 = 0.f, a5 = 0.f, a6 = 0.f, a7 = 0.f;

  if ((g & 7) == 0) {  // self terms: group 0 -> node0, group 8 -> node1
    uint4 v = hp4[(size_t)(nh ? p1c : p0c) * (H2 / 8) + j];
    ACC8(v);
  }

  int mx = max(r01 - r00, r11 - r01);
  for (int kk = 0; kk * 16 < mx; ++kk) {
    int b0 = r00 + 16 * kk, b1e = r01 + 16 * kk;
    int ci = (lane < 32) ? min(b0 + (lane & 15), r01 - 1)
                         : min(b1e + (lane & 15), r11 - 1);
    int s = csr[max(ci, 0)];
#pragma unroll
    for (int it = 0; it < 2; ++it) {
      int e = it * 8 + (g & 7);
      int sv = __shfl(s, (nh ? 32 : 0) + e, 64);
      int eidx = (nh ? b1e : b0) + e;
      int lim = nh ? r11 : r01;
      if (eidx < lim) {
        uint4 v = hp4[(size_t)sv * (H2 / 8) + j];   // 8+8 edges / instruction
        ACC8(v);
      }
    }
  }
  RED8(4); RED8(8); RED8(16);  // reduce across the 8 groups of each node-half

  float d = (lane < 32) ? d0 : d1;
  if ((lane & 31) < 4) {   // lane j holds cols [8j, 8j+8) of its node
    int jj = lane & 3, nn = lane >> 5;
    float4 v0, v1;
    v0.x = a0 * d + b2s[8 * jj + 0];
    v0.y = a1 * d + b2s[8 * jj + 1];
    v0.z = a2 * d + b2s[8 * jj + 2];
    v0.w = a3 * d + b2s[8 * jj + 3];
    v1.x = a4 * d + b2s[8 * jj + 4];
    v1.y = a5 * d + b2s[8 * jj + 5];
    v1.z = a6 * d + b2s[8 * jj + 6];
    v1.w = a7 * d + b2s[8 * jj + 7];
    *(float4*)&rowh[wv][nn][8 * jj + 0] = v0;
    *(float4*)&rowh[wv][nn][8 * jj + 4] = v1;
  }
  __syncthreads();

  // gates: lane -> (node = lane>>5, f = lane&31); full k loop
  int node = lane >> 5, f = lane & 31;
  float gacc = 0.f;
#pragma unroll
  for (int k = 0; k < H2; ++k) gacc += rowh[wv][node][k] * gwt[k][f];
  rowg[wv][node][f] = 1.0f / (1.0f + __expf(-(gacc + gate_b[f])));
  __syncthreads();

  // leaf: within each 32-half, 4 groups of 8 lanes partial-sum then xor-reduce
  int c = lane & 7, gi = (lane >> 3) & 3;
  float a = 0.f;
#pragma unroll
  for (int j8 = 0; j8 < 8; ++j8) {
    int jj = gi * 8 + j8;
    a += rowg[wv][node][jj] * lws[jj][c];
  }
  a += __shfl_xor(a, 8, 64);
  a += __shfl_xor(a, 16, 64);
  int wout = p0n + node;
  if ((lane & 31) < 8 && wout < n) out[(size_t)wout * NC + c] = a;
}

// ---------------- host ----------------

static inline size_t align256(size_t x) { return (x + 255) & ~(size_t)255; }

extern "C" void kernel_launch(void* const* d_in, const int* in_sizes, int n_in,
                              void* d_out, int out_size, void* d_ws, size_t ws_size,
                              hipStream_t stream) {
  const float* x  = (const float*)d_in[0];
  const int*   ei = (const int*)d_in[1];
  const float* W1 = (const float*)d_in[2];
  const float* b1 = (const float*)d_in[3];
  const float* W2 = (const float*)d_in[4];
  const float* b2 = (const float*)d_in[5];
  const float* gw = (const float*)d_in[6];
  const float* gb = (const float*)d_in[7];
  const float* lw = (const float*)d_in[8];
  float* out = (float*)d_out;

  int n = in_sizes[0] / IN_DIM;
  int E = in_sizes[1] / 2;
  const int* src  = ei;
  const int* dstp = ei + E;

  int NBk = (n + 255) >> 8;                    // buckets of 256 nodes
  int EPB = (E + BLK - 1) / BLK;               // edges per partition block
  int L   = NBk * BLK;                         // blockhist entries
  int nbs = (L + SCAN_CH - 1) / SCAN_CH;       // scan blocks

  // workspace layout: hot gather tables FIRST (256B-aligned; R17 straddle fix)
  char* w = (char*)d_ws;
  unsigned short* h1p = (unsigned short*)w;  w += align256((size_t)n * H1 * 2);  // bf16 [n][64]
  unsigned short* h2p = (unsigned short*)w;  w += align256((size_t)n * H2 * 2);  // bf16 [n][32]
  int* csr    = (int*)w;   w += align256((size_t)E * 4);
  u32* packed = (u32*)w;   w += align256((size_t)E * 4);
  int* bh     = (int*)w;   w += align256(((size_t)L + 1) * 4);
  int* S      = (int*)w;   w += align256(((size_t)L + 1) * 4);
  int* bsum   = (int*)w;   w += align256((size_t)nbs * 4);
  int* bbase  = (int*)w;   w += align256((size_t)nbs * 4);
  float* dinv = (float*)w; w += align256((size_t)n * 4);
  int* off    = (int*)w;   w += align256(((size_t)n + 1) * 4);

  int gw8 = (n + 7) / 8;  // 8 nodes per 256-thread block (2 per wave)

  k_hist<<<BLK, 256, 0, stream>>>(dstp, bh, E, EPB, NBk);
  k_gsc1<<<nbs, 256, 0, stream>>>(bh, bsum, L);
  k_gsc2<<<1, 256, 0, stream>>>(bsum, bbase, S, nbs, L);
  k_gsc3<<<nbs, 256, 0, stream>>>(bh, bbase, S, L);
  k_scatter<<<BLK, 256, 0, stream>>>(src, dstp, S, packed, E, EPB, NBk);
  k_build<<<NBk, 256, 0, stream>>>(packed, S, csr, off, dinv, n, NBk);

  k_proj1<<<(n + 15) / 16, 256, 0, stream>>>((const float4*)x, W1, dinv, h1p, n);
  k_agg64_proj2<<<gw8, 256, 0, stream>>>((const u32*)h1p, dinv, off, csr, b1, W2, h2p, n);
  k_agg32_tree<<<gw8, 256, 0, stream>>>((const u32*)h2p, dinv, off, csr, b2, gw, gb, lw, out, n);
}

// Round 6
// 347.771 us; speedup vs baseline: 6.5917x; 1.0089x over previous
//
#include <hip/hip_runtime.h>
#include <math.h>

#define IN_DIM 128
#define H1 64
#define H2 32
#define NC 8
#define SCAN_CH 1024   // elements per scan block (256 threads x 4)
#define NB_MAX 512     // max buckets (n <= 131072)
#define BLK 512        // edge partition blocks
#define CAP 12288      // LDS staging capacity per bucket (entries)

typedef unsigned int u32;

__device__ __forceinline__ float bf_lo(u32 u) { return __uint_as_float(u << 16); }
__device__ __forceinline__ float bf_hi(u32 u) { return __uint_as_float(u & 0xffff0000u); }
__device__ __forceinline__ unsigned short f2b(float f) {  // RNE float->bf16
  u32 u = __float_as_uint(f);
  u += 0x7fffu + ((u >> 16) & 1u);
  return (unsigned short)(u >> 16);
}

// ---------------- P1: per-block bucket histogram (LDS atomics only) ----------------
// bucket(d) = d >> 8 (256 nodes per bucket).

__global__ __launch_bounds__(256) void k_hist(const int* __restrict__ dst,
                                              int* __restrict__ bh,
                                              int E, int EPB, int NBk) {
  __shared__ int h[NB_MAX];
  int k = blockIdx.x, tid = threadIdx.x;
  for (int i = tid; i < NBk; i += 256) h[i] = 0;
  __syncthreads();
  int st = k * EPB, en = min(E, st + EPB);
  for (int i = st + tid; i < en; i += 256)
    atomicAdd(&h[((u32)dst[i]) >> 8], 1);
  __syncthreads();
  for (int b = tid; b < NBk; b += 256) bh[b * BLK + k] = h[b];
}

// ---- generic 3-phase exclusive scan of A[L] -> S[L], S[L] = total ----

__global__ __launch_bounds__(256) void k_gsc1(const int* __restrict__ A,
                                              int* __restrict__ bsum, int L) {
  int b = blockIdx.x, tid = threadIdx.x;
  int i0 = b * SCAN_CH + tid * 4;
  int s = 0;
  if (i0 + 3 < L) {
    int4 v = *(const int4*)(A + i0);
    s = v.x + v.y + v.z + v.w;
  } else {
    for (int i = i0; i < L; ++i) s += A[i];
  }
  __shared__ int red[256];
  red[tid] = s;
  __syncthreads();
  for (int d = 128; d > 0; d >>= 1) {
    if (tid < d) red[tid] += red[tid + d];
    __syncthreads();
  }
  if (tid == 0) bsum[b] = red[0];
}

__global__ __launch_bounds__(256) void k_gsc2(const int* __restrict__ bsum,
                                              int* __restrict__ bbase,
                                              int* __restrict__ S, int nbk, int L) {
  __shared__ int part[256];
  int tid = threadIdx.x;
  int chunk = (nbk + 255) / 256;
  int st = tid * chunk, en = min(st + chunk, nbk);
  int s = 0;
  for (int i = st; i < en; ++i) s += bsum[i];
  part[tid] = s;
  __syncthreads();
  for (int d = 1; d < 256; d <<= 1) {
    int t = (tid >= d) ? part[tid - d] : 0;
    __syncthreads();
    part[tid] += t;
    __syncthreads();
  }
  int base = (tid == 0) ? 0 : part[tid - 1];
  for (int i = st; i < en; ++i) { bbase[i] = base; base += bsum[i]; }
  if (tid == 255) S[L] = part[255];
}

__global__ __launch_bounds__(256) void k_gsc3(const int* __restrict__ A,
                                              const int* __restrict__ bbase,
                                              int* __restrict__ S, int L) {
  int b = blockIdx.x, tid = threadIdx.x;
  int i0 = b * SCAN_CH + tid * 4;
  int e0 = 0, e1 = 0, e2 = 0, e3 = 0;
  if (i0 + 3 < L) {
    int4 v = *(const int4*)(A + i0);
    e0 = v.x; e1 = v.y; e2 = v.z; e3 = v.w;
  } else {
    if (i0 + 0 < L) e0 = A[i0 + 0];
    if (i0 + 1 < L) e1 = A[i0 + 1];
    if (i0 + 2 < L) e2 = A[i0 + 2];
    if (i0 + 3 < L) e3 = A[i0 + 3];
  }
  __shared__ int part[256];
  part[tid] = e0 + e1 + e2 + e3;
  __syncthreads();
  for (int d = 1; d < 256; d <<= 1) {
    int t = (tid >= d) ? part[tid - d] : 0;
    __syncthreads();
    part[tid] += t;
    __syncthreads();
  }
  int base = bbase[b] + ((tid == 0) ? 0 : part[tid - 1]);
  int o0 = base, o1 = o0 + e0, o2 = o1 + e1, o3 = o2 + e2;
  if (i0 + 3 < L) {
    int4 o; o.x = o0; o.y = o1; o.z = o2; o.w = o3;
    *(int4*)(S + i0) = o;
  } else {
    if (i0 + 0 < L) S[i0 + 0] = o0;
    if (i0 + 1 < L) S[i0 + 1] = o1;
    if (i0 + 2 < L) S[i0 + 2] = o2;
    if (i0 + 3 < L) S[i0 + 3] = o3;
  }
}

// ---------------- P3: bucket scatter (LDS cursors, disjoint global ranges) ----------------
// packed entry: bits[0,17) = src, bits[17,25) = local node id within bucket.

__global__ __launch_bounds__(256) void k_scatter(const int* __restrict__ src,
                                                 const int* __restrict__ dst,
                                                 const int* __restrict__ S,
                                                 u32* __restrict__ packed,
                                                 int E, int EPB, int NBk) {
  __shared__ int cur[NB_MAX];
  int k = blockIdx.x, tid = threadIdx.x;
  for (int b = tid; b < NBk; b += 256) cur[b] = S[b * BLK + k];
  __syncthreads();
  int st = k * EPB, en = min(E, st + EPB);
  for (int i = st + tid; i < en; i += 256) {
    int d = dst[i];
    int b = ((u32)d) >> 8;
    int pos = atomicAdd(&cur[b], 1);
    packed[pos] = (((u32)d & 255u) << 17) | (u32)src[i];
  }
}

// ---------------- P4: per-bucket CSR build + off + dinv ----------------

__global__ __launch_bounds__(256) void k_build(const u32* __restrict__ packed,
                                               const int* __restrict__ S,
                                               int* __restrict__ csr,
                                               int* __restrict__ off,
                                               float* __restrict__ dinv,
                                               int n, int NBk) {
  __shared__ int cnt[256];
  __shared__ int tmp[256];
  __shared__ int cur[256];
  __shared__ int sbuf[CAP];  // 48 KB staging
  int b = blockIdx.x, tid = threadIdx.x;
  int r0 = S[b * BLK];
  int r1 = S[(b + 1) * BLK];  // for last bucket: S[L] = E
  int m = r1 - r0;
  cnt[tid] = 0;
  __syncthreads();
  for (int i = r0 + tid; i < r1; i += 256)
    atomicAdd(&cnt[packed[i] >> 17], 1);
  __syncthreads();
  int v = cnt[tid];
  tmp[tid] = v;
  __syncthreads();
  for (int d = 1; d < 256; d <<= 1) {
    int t = (tid >= d) ? tmp[tid - d] : 0;
    __syncthreads();
    tmp[tid] += t;
    __syncthreads();
  }
  int rel = tmp[tid] - v;  // exclusive prefix within bucket
  int node = b * 256 + tid;
  if (node < n) {
    off[node] = r0 + rel;
    dinv[node] = rsqrtf((float)(v + 1));  // +1 self-loop
  }
  if (b == NBk - 1 && tid == 0) off[n] = r1;
  cur[tid] = rel;
  __syncthreads();
  if (m <= CAP) {
    for (int i = r0 + tid; i < r1; i += 256) {
      u32 u = packed[i];
      int pos = atomicAdd(&cur[u >> 17], 1);
      sbuf[pos] = (int)(u & 0x1FFFFu);
    }
    __syncthreads();
    for (int j = tid; j < m; j += 256)
      csr[r0 + j] = sbuf[j];
  } else {
    for (int i = r0 + tid; i < r1; i += 256) {
      u32 u = packed[i];
      int pos = atomicAdd(&cur[u >> 17], 1);
      csr[r0 + pos] = (int)(u & 0x1FFFFu);
    }
  }
}

// ---------------- projection 1: h1p = bf16(dinv * (x @ W1^T))  [n,128]->[n,64] ----------------

__global__ void k_proj1(const float4* __restrict__ x4, const float* __restrict__ W1,
                        const float* __restrict__ dinv,
                        unsigned short* __restrict__ h1p, int n) {
  __shared__ float xs[16][IN_DIM];
  __shared__ float wt[IN_DIM][H1 + 1];
  int tid = threadIdx.x;
  int row0 = blockIdx.x * 16;

  for (int i = tid; i < (H1 * IN_DIM / 4); i += 256) {
    float4 w = ((const float4*)W1)[i];
    int o = (i * 4) / IN_DIM;
    int k = (i * 4) % IN_DIM;
    wt[k + 0][o] = w.x; wt[k + 1][o] = w.y; wt[k + 2][o] = w.z; wt[k + 3][o] = w.w;
  }
  for (int i = tid; i < 16 * IN_DIM / 4; i += 256) {
    int r = (i * 4) / IN_DIM, k = (i * 4) % IN_DIM;
    int row = row0 + r;
    if (row < n)
      *((float4*)&xs[r][k]) = x4[(size_t)row * (IN_DIM / 4) + k / 4];
  }
  __syncthreads();

  int o = tid & 63, rq = tid >> 6;
  float a0 = 0.f, a1 = 0.f, a2 = 0.f, a3 = 0.f;
  for (int k = 0; k < IN_DIM; ++k) {
    float w = wt[k][o];
    a0 += xs[rq * 4 + 0][k] * w;
    a1 += xs[rq * 4 + 1][k] * w;
    a2 += xs[rq * 4 + 2][k] * w;
    a3 += xs[rq * 4 + 3][k] * w;
  }
  int r = row0 + rq * 4;
  if (r + 0 < n) h1p[(size_t)(r + 0) * H1 + o] = f2b(a0 * dinv[r + 0]);
  if (r + 1 < n) h1p[(size_t)(r + 1) * H1 + o] = f2b(a1 * dinv[r + 1]);
  if (r + 2 < n) h1p[(size_t)(r + 2) * H1 + o] = f2b(a2 * dinv[r + 2]);
  if (r + 3 < n) h1p[(size_t)(r + 3) * H1 + o] = f2b(a3 * dinv[r + 3]);
}

// ---------------- fused: layer-1 gather-agg + bias + relu + proj2 ----------------
// R19: FOUR independent nodes per wave. Per batch: one csr load carries 16 ids
// per node (lanes [16*node, 16*node+16)); 8 gather instrs back-to-back, each
// covering 2 edges of each of the 4 nodes (8 groups of 8 lanes). 2x chains and
// 2x in-flight gathers per wave slot vs R18.

#define ACC8(v) do { \
    a0 += bf_lo((v).x); a1 += bf_hi((v).x); \
    a2 += bf_lo((v).y); a3 += bf_hi((v).y); \
    a4 += bf_lo((v).z); a5 += bf_hi((v).z); \
    a6 += bf_lo((v).w); a7 += bf_hi((v).w); } while (0)

#define RED8(m) do { \
    a0 += __shfl_xor(a0, m, 64); a1 += __shfl_xor(a1, m, 64); \
    a2 += __shfl_xor(a2, m, 64); a3 += __shfl_xor(a3, m, 64); \
    a4 += __shfl_xor(a4, m, 64); a5 += __shfl_xor(a5, m, 64); \
    a6 += __shfl_xor(a6, m, 64); a7 += __shfl_xor(a7, m, 64); } while (0)

__global__ __launch_bounds__(256) void k_agg64_proj2(
    const u32* __restrict__ hp,    // [n][32] packed bf16x2 (= [n][8] uint4)
    const float* __restrict__ dinv,
    const int* __restrict__ off, const int* __restrict__ csr,
    const float* __restrict__ b1, const float* __restrict__ W2,
    unsigned short* __restrict__ h2p, int n) {
  __shared__ float wt[H1][H2 + 1];   // W2 transposed: wt[k][o]
  __shared__ float rows[4][4][H1];   // relu(out1) rows, 4 nodes per wave
  __shared__ float b1s[H1];
  int tid = threadIdx.x;

  for (int i = tid; i < H2 * H1 / 4; i += 256) {
    float4 w = ((const float4*)W2)[i];
    int o = (i * 4) / H1, k = (i * 4) % H1;
    wt[k + 0][o] = w.x; wt[k + 1][o] = w.y; wt[k + 2][o] = w.z; wt[k + 3][o] = w.w;
  }
  if (tid < 16) ((float4*)b1s)[tid] = ((const float4*)b1)[tid];
  __syncthreads();

  int lane = tid & 63;
  int wv = __builtin_amdgcn_readfirstlane(tid >> 6);
  int p0 = (blockIdx.x * 4 + wv) * 4;        // first of this wave's 4 nodes
  int g = lane >> 3, j = lane & 7;           // 8 groups of 8 lanes; lane j reads 16B
  int nh = g >> 1, gg = g & 1;               // node of this group, sub-slot

  // off[p0 .. p0+4] via one load + shfl (wave-uniform ranges)
  int tt = 0;
  if (lane < 5) tt = off[min(p0 + lane, n)];
  int r0 = __shfl(tt, 0, 64), r1 = __shfl(tt, 1, 64), r2 = __shfl(tt, 2, 64),
      r3 = __shfl(tt, 3, 64), r4 = __shfl(tt, 4, 64);
  float dv = 0.f;
  if (lane < 4) dv = dinv[min(p0 + lane, n - 1)];
  float d0 = __shfl(dv, 0, 64), d1 = __shfl(dv, 1, 64),
        d2 = __shfl(dv, 2, 64), d3 = __shfl(dv, 3, 64);

  // per-lane node-selected range / norm
  int rB = (nh == 0) ? r1 : (nh == 1) ? r2 : (nh == 2) ? r3 : r4;
  int rA = (nh == 0) ? r0 : (nh == 1) ? r1 : (nh == 2) ? r2 : r3;
  int mydeg = rB - rA;
  float dN = (nh == 0) ? d0 : (nh == 1) ? d1 : (nh == 2) ? d2 : d3;

  // csr-load lane mapping: lane ln = lane>>4 serves node ln, 16 ids/batch
  int ln = lane >> 4, pos = lane & 15;
  int cA = (ln == 0) ? r0 : (ln == 1) ? r1 : (ln == 2) ? r2 : r3;
  int cB = (ln == 0) ? r1 : (ln == 1) ? r2 : (ln == 2) ? r3 : r4;

  const uint4* __restrict__ hp4 = (const uint4*)hp;
  float a0 = 0.f, a1 = 0.f, a2 = 0.f, a3 = 0.f,
        a4 = 0.f, a5 = 0.f, a6 = 0.f, a7 = 0.f;

  if (gg == 0) {  // self term of node nh (table has dinv[self] folded in)
    uint4 v = hp4[(size_t)min(p0 + nh, n - 1) * (H1 / 8) + j];
    ACC8(v);
  }

  int mx = max(max(r1 - r0, r2 - r1), max(r3 - r2, r4 - r3));
  for (int kk = 0; kk * 16 < mx; ++kk) {
    int ci = cA + 16 * kk + pos;
    ci = max(min(ci, cB - 1), 0);
    int s = csr[ci];                 // 16 ids per node, one coalesced load
#pragma unroll
    for (int it = 0; it < 8; ++it) {
      int e = it * 2 + gg;
      int sv = __shfl(s, nh * 16 + e, 64);
      if (16 * kk + e < mydeg) {
        uint4 v = hp4[(size_t)sv * (H1 / 8) + j];   // 2 edges/node/instruction
        ACC8(v);
      }
    }
  }
  RED8(8);  // combine the 2 sub-slots of each node

  if (gg == 0) {   // lane holds cols [8j, 8j+8) of node nh
    float4 v0, v1;
    v0.x = fmaxf(a0 * dN + b1s[8 * j + 0], 0.f);
    v0.y = fmaxf(a1 * dN + b1s[8 * j + 1], 0.f);
    v0.z = fmaxf(a2 * dN + b1s[8 * j + 2], 0.f);
    v0.w = fmaxf(a3 * dN + b1s[8 * j + 3], 0.f);
    v1.x = fmaxf(a4 * dN + b1s[8 * j + 4], 0.f);
    v1.y = fmaxf(a5 * dN + b1s[8 * j + 5], 0.f);
    v1.z = fmaxf(a6 * dN + b1s[8 * j + 6], 0.f);
    v1.w = fmaxf(a7 * dN + b1s[8 * j + 7], 0.f);
    *(float4*)&rows[wv][nh][8 * j + 0] = v0;
    *(float4*)&rows[wv][nh][8 * j + 4] = v1;
  }
  __syncthreads();

  // proj2: 4 nodes x 32 outputs per wave; 2 per lane
  int o = lane & 31;
#pragma unroll
  for (int t = 0; t < 2; ++t) {
    int node = (lane >> 5) + 2 * t;
    float a = 0.f;
#pragma unroll
    for (int k = 0; k < H1; ++k) a += rows[wv][node][k] * wt[k][o];
    float dd = (node == 0) ? d0 : (node == 1) ? d1 : (node == 2) ? d2 : d3;
    if (p0 + node < n) h2p[(size_t)(p0 + node) * H2 + o] = f2b(a * dd);
  }
}

// ---------------- fused: layer-2 gather-agg + b2 + gates + leaf ----------------
// R19: four nodes per wave; 16 groups of 4 lanes, 4 groups per node.

__global__ __launch_bounds__(256) void k_agg32_tree(
    const u32* __restrict__ hp,    // [n][16] packed bf16x2 (= [n][4] uint4)
    const float* __restrict__ dinv,
    const int* __restrict__ off, const int* __restrict__ csr,
    const float* __restrict__ b2, const float* __restrict__ gate_w,
    const float* __restrict__ gate_b, const float* __restrict__ leaf_w,
    float* __restrict__ out, int n) {
  __shared__ float gwt[H2][H2 + 1];  // gate_w transposed: gwt[k][j]
  __shared__ float lws[H2][NC + 1];
  __shared__ float rowh[4][4][H2];
  __shared__ float rowg[4][2][H2];
  __shared__ float b2s[H2];
  int tid = threadIdx.x;

  {
    float4 w = ((const float4*)gate_w)[tid];  // H2*H2/4 == 256
    int jj = (tid * 4) / H2, k = (tid * 4) % H2;
    gwt[k + 0][jj] = w.x; gwt[k + 1][jj] = w.y; gwt[k + 2][jj] = w.z; gwt[k + 3][jj] = w.w;
  }
  lws[tid >> 3][tid & 7] = leaf_w[tid];  // H2*NC == 256
  if (tid < 8) ((float4*)b2s)[tid] = ((const float4*)b2)[tid];
  __syncthreads();

  int lane = tid & 63;
  int wv = __builtin_amdgcn_readfirstlane(tid >> 6);
  int p0 = (blockIdx.x * 4 + wv) * 4;
  int g = lane >> 2, j = lane & 3;   // 16 groups of 4 lanes; lane j reads 16B
  int nh = g >> 2, gg = g & 3;       // node of this group, sub-slot

  int tt = 0;
  if (lane < 5) tt = off[min(p0 + lane, n)];
  int r0 = __shfl(tt, 0, 64), r1 = __shfl(tt, 1, 64), r2 = __shfl(tt, 2, 64),
      r3 = __shfl(tt, 3, 64), r4 = __shfl(tt, 4, 64);
  float dv = 0.f;
  if (lane < 4) dv = dinv[min(p0 + lane, n - 1)];
  float d0 = __shfl(dv, 0, 64), d1 = __shfl(dv, 1, 64),
        d2 = __shfl(dv, 2, 64), d3 = __shfl(dv, 3, 64);

  int rB = (nh == 0) ? r1 : (nh == 1) ? r2 : (nh == 2) ? r3 : r4;
  int rA = (nh == 0) ? r0 : (nh == 1) ? r1 : (nh == 2) ? r2 : r3;
  int mydeg = rB - rA;
  float dN = (nh == 0) ? d0 : (nh == 1) ? d1 : (nh == 2) ? d2 : d3;

  int ln = lane >> 4, pos = lane & 15;
  int cA = (ln == 0) ? r0 : (ln == 1) ? r1 : (ln == 2) ? r2 : r3;
  int cB = (ln == 0) ? r1 : (ln == 1) ? r2 : (ln == 2) ? r3 : r4;

  const uint4* __restrict__ hp4 = (const uint4*)hp;
  float a0 = 0.f, a1 = 0.f, a2 = 0.f, a3 = 0.f,
        a4 = 0.f, a5 = 0.f, a6 = 0.f, a7 = 0.f;

  if (gg == 0) {  // self term of node nh
    uint4 v = hp4[(size_t)min(p0 + nh, n - 1) * (H2 / 8) + j];
    ACC8(v);
  }

  int mx = max(max(r1 - r0, r2 - r1), max(r3 - r2, r4 - r3));
  for (int kk = 0; kk * 16 < mx; ++kk) {
    int ci = cA + 16 * kk + pos;
    ci = max(min(ci, cB - 1), 0);
    int s = csr[ci];
#pragma unroll
    for (int it = 0; it < 4; ++it) {
      int e = it * 4 + gg;
      int sv = __shfl(s, nh * 16 + e, 64);
      if (16 * kk + e < mydeg) {
        uint4 v = hp4[(size_t)sv * (H2 / 8) + j];   // 4 edges/node/instruction
        ACC8(v);
      }
    }
  }
  RED8(4); RED8(8);  // combine the 4 sub-slots of each node

  if (gg == 0) {   // lane holds cols [8j, 8j+8) of node nh (j = 0..3)
    float4 v0, v1;
    v0.x = a0 * dN + b2s[8 * j + 0];
    v0.y = a1 * dN + b2s[8 * j + 1];
    v0.z = a2 * dN + b2s[8 * j + 2];
    v0.w = a3 * dN + b2s[8 * j + 3];
    v1.x = a4 * dN + b2s[8 * j + 4];
    v1.y = a5 * dN + b2s[8 * j + 5];
    v1.z = a6 * dN + b2s[8 * j + 6];
    v1.w = a7 * dN + b2s[8 * j + 7];
    *(float4*)&rowh[wv][nh][8 * j + 0] = v0;
    *(float4*)&rowh[wv][nh][8 * j + 4] = v1;
  }
  __syncthreads();

  // gates + leaf: 4 nodes per wave, 2 per pass (half-wave per node)
#pragma unroll
  for (int t = 0; t < 2; ++t) {
    int node = (lane >> 5) + 2 * t;
    int f = lane & 31;
    float gacc = 0.f;
#pragma unroll
    for (int k = 0; k < H2; ++k) gacc += rowh[wv][node][k] * gwt[k][f];
    rowg[wv][lane >> 5][f] = 1.0f / (1.0f + __expf(-(gacc + gate_b[f])));
    __syncthreads();

    int c = lane & 7, gi = (lane >> 3) & 3;
    float a = 0.f;
#pragma unroll
    for (int j8 = 0; j8 < 8; ++j8) {
      int jj = gi * 8 + j8;
      a += rowg[wv][lane >> 5][jj] * lws[jj][c];
    }
    a += __shfl_xor(a, 8, 64);
    a += __shfl_xor(a, 16, 64);
    if ((lane & 31) < 8 && p0 + node < n) out[(size_t)(p0 + node) * NC + c] = a;
    __syncthreads();
  }
}

// ---------------- host ----------------

static inline size_t align256(size_t x) { return (x + 255) & ~(size_t)255; }

extern "C" void kernel_launch(void* const* d_in, const int* in_sizes, int n_in,
                              void* d_out, int out_size, void* d_ws, size_t ws_size,
                              hipStream_t stream) {
  const float* x  = (const float*)d_in[0];
  const int*   ei = (const int*)d_in[1];
  const float* W1 = (const float*)d_in[2];
  const float* b1 = (const float*)d_in[3];
  const float* W2 = (const float*)d_in[4];
  const float* b2 = (const float*)d_in[5];
  const float* gw = (const float*)d_in[6];
  const float* gb = (const float*)d_in[7];
  const float* lw = (const float*)d_in[8];
  float* out = (float*)d_out;

  int n = in_sizes[0] / IN_DIM;
  int E = in_sizes[1] / 2;
  const int* src  = ei;
  const int* dstp = ei + E;

  int NBk = (n + 255) >> 8;                    // buckets of 256 nodes
  int EPB = (E + BLK - 1) / BLK;               // edges per partition block
  int L   = NBk * BLK;                         // blockhist entries
  int nbs = (L + SCAN_CH - 1) / SCAN_CH;       // scan blocks

  // workspace layout: hot gather tables FIRST (256B-aligned; R17 straddle fix)
  char* w = (char*)d_ws;
  unsigned short* h1p = (unsigned short*)w;  w += align256((size_t)n * H1 * 2);  // bf16 [n][64]
  unsigned short* h2p = (unsigned short*)w;  w += align256((size_t)n * H2 * 2);  // bf16 [n][32]
  int* csr    = (int*)w;   w += align256((size_t)E * 4);
  u32* packed = (u32*)w;   w += align256((size_t)E * 4);
  int* bh     = (int*)w;   w += align256(((size_t)L + 1) * 4);
  int* S      = (int*)w;   w += align256(((size_t)L + 1) * 4);
  int* bsum   = (int*)w;   w += align256((size_t)nbs * 4);
  int* bbase  = (int*)w;   w += align256((size_t)nbs * 4);
  float* dinv = (float*)w; w += align256((size_t)n * 4);
  int* off    = (int*)w;   w += align256(((size_t)n + 1) * 4);

  int gw16 = (n + 15) / 16;  // 16 nodes per 256-thread block (4 per wave)

  k_hist<<<BLK, 256, 0, stream>>>(dstp, bh, E, EPB, NBk);
  k_gsc1<<<nbs, 256, 0, stream>>>(bh, bsum, L);
  k_gsc2<<<1, 256, 0, stream>>>(bsum, bbase, S, nbs, L);
  k_gsc3<<<nbs, 256, 0, stream>>>(bh, bbase, S, L);
  k_scatter<<<BLK, 256, 0, stream>>>(src, dstp, S, packed, E, EPB, NBk);
  k_build<<<NBk, 256, 0, stream>>>(packed, S, csr, off, dinv, n, NBk);

  k_proj1<<<(n + 15) / 16, 256, 0, stream>>>((const float4*)x, W1, dinv, h1p, n);
  k_agg64_proj2<<<gw16, 256, 0, stream>>>((const u32*)h1p, dinv, off, csr, b1, W2, h2p, n);
  k_agg32_tree<<<gw16, 256, 0, stream>>>((const u32*)h2p, dinv, off, csr, b2, gw, gb, lw, out, n);
}